// Round 1
// baseline (6935.279 us; speedup 1.0000x reference)
//
#include <hip/hip_runtime.h>

namespace {
constexpr int kB = 2048;
constexpr int kT = 72;
constexpr int kI = 200;
constexpr int kH = 200;
constexpr int kO = 53;
constexpr int kG = 600;   // 3*kH
constexpr int BTILE = 8;
constexpr int NWG = kB / BTILE;   // 256

// ws layout (float offsets)
constexpr int WT_HH1 = 0;        // [200][600] transposed Whh1
constexpr int WT_IH2 = 120000;
constexpr int WT_HH2 = 240000;
constexpr int WT_IH3 = 360000;
constexpr int WT_HH3 = 480000;
constexpr int WIH1T  = 600000;   // [200][600] transposed Wih1 (prep only)
constexpr int FCINT  = 720000;   // [200][200] transposed fc_in_W (prep only)
constexpr int XW1    = 760000;   // [2048][600] emb@Wih1^T + bih1

// output offsets (floats)
constexpr int OH1 = kB * kT * kO;      // 7815168
constexpr int OH2 = OH1 + kB * kH;
constexpr int OH3 = OH2 + kB * kH;
}

__device__ __forceinline__ float sig_(float x) { return 1.0f / (1.0f + __expf(-x)); }
__device__ __forceinline__ float tanh_(float x) {
    // (e^2x-1)/(e^2x+1); inf-safe at both ends
    return 1.0f - 2.0f / (__expf(2.0f * x) + 1.0f);
}

__global__ __launch_bounds__(256) void prep_transpose(
    const float* __restrict__ Whh1, const float* __restrict__ Wih2,
    const float* __restrict__ Whh2, const float* __restrict__ Wih3,
    const float* __restrict__ Whh3, const float* __restrict__ Wih1,
    const float* __restrict__ fciW, float* __restrict__ ws) {
    int idx = blockIdx.x * 256 + threadIdx.x;
    if (idx < 6 * 120000) {
        int m = idx / 120000;
        int rem = idx - m * 120000;
        int k = rem / kG;
        int c = rem - k * kG;
        const float* src; int dst;
        switch (m) {
            case 0: src = Whh1; dst = WT_HH1; break;
            case 1: src = Wih2; dst = WT_IH2; break;
            case 2: src = Whh2; dst = WT_HH2; break;
            case 3: src = Wih3; dst = WT_IH3; break;
            case 4: src = Whh3; dst = WT_HH3; break;
            default: src = Wih1; dst = WIH1T; break;
        }
        ws[dst + rem] = src[c * kH + k];
    } else {
        int i = idx - 720000;
        if (i < 40000) {
            int k = i / kH, h = i - k * kH;
            ws[FCINT + i] = fciW[h * kI + k];
        }
    }
}

// One block per batch row: BN -> fc_in+ReLU -> xw1 = emb@Wih1^T + bih1
__global__ __launch_bounds__(256) void prep_input(
    const float* __restrict__ enc,
    const float* __restrict__ bn_g, const float* __restrict__ bn_b,
    const float* __restrict__ bn_m, const float* __restrict__ bn_v,
    const float* __restrict__ fcib, const float* __restrict__ bih1,
    float* ws) {
    __shared__ float xh[kI];
    __shared__ float emb[kH];
    const int b = blockIdx.x, tid = threadIdx.x;
    const float* fcInT = ws + FCINT;
    const float* Wih1T = ws + WIH1T;
    if (tid < kI) {
        float x = enc[b * kI + tid];
        xh[tid] = (x - bn_m[tid]) * rsqrtf(bn_v[tid] + 1e-5f) * bn_g[tid] + bn_b[tid];
    }
    __syncthreads();
    if (tid < kH) {
        float s = fcib[tid];
        for (int k = 0; k < kI; ++k) s = fmaf(xh[k], fcInT[k * kH + tid], s);
        emb[tid] = fmaxf(s, 0.0f);
    }
    __syncthreads();
    for (int c = tid; c < kG; c += 256) {
        float s = bih1[c];
        for (int k = 0; k < kH; ++k) s = fmaf(emb[k], Wih1T[k * kG + c], s);
        ws[XW1 + b * kG + c] = s;
    }
}

// Persistent fused 3-layer GRU scan. One WG per 8 batch rows. Thread j<200
// owns hidden unit j (computes r,z,n gate columns j, 200+j, 400+j).
__global__ __launch_bounds__(256, 1) void gru_main(
    const float* __restrict__ ws,
    const float* __restrict__ h1in, const float* __restrict__ h2in,
    const float* __restrict__ h3in,
    const float* __restrict__ bhh1,
    const float* __restrict__ bih2, const float* __restrict__ bhh2,
    const float* __restrict__ bih3, const float* __restrict__ bhh3,
    const float* __restrict__ fcoW, const float* __restrict__ fcob,
    float* __restrict__ out) {
    __shared__ float h1s[BTILE][kH];
    __shared__ float h2s[BTILE][kH];
    __shared__ float h3s[BTILE][kH];

    const int j = threadIdx.x;
    const int b0 = blockIdx.x * BTILE;
    const bool act = (j < kH);

    float xr[BTILE], xz[BTILE], xn[BTILE];
    float b1n = 0, b2r = 0, b2z = 0, b2xn = 0, b2hn = 0;
    float b3r = 0, b3z = 0, b3xn = 0, b3hn = 0;

    if (act) {
        float b1r = bhh1[j], b1z = bhh1[kH + j];
        b1n = bhh1[2 * kH + j];
        b2r = bih2[j] + bhh2[j];
        b2z = bih2[kH + j] + bhh2[kH + j];
        b2xn = bih2[2 * kH + j];
        b2hn = bhh2[2 * kH + j];
        b3r = bih3[j] + bhh3[j];
        b3z = bih3[kH + j] + bhh3[kH + j];
        b3xn = bih3[2 * kH + j];
        b3hn = bhh3[2 * kH + j];
        #pragma unroll
        for (int r = 0; r < BTILE; ++r) {
            int b = b0 + r;
            h1s[r][j] = h1in[b * kH + j];
            h2s[r][j] = h2in[b * kH + j];
            h3s[r][j] = h3in[b * kH + j];
            const float* xw = ws + XW1 + b * kG;
            xr[r] = xw[j] + b1r;          // xw1 includes bih1; fold bhh1 r/z
            xz[r] = xw[kH + j] + b1z;
            xn[r] = xw[2 * kH + j];       // bhh1_n stays separate (inside r*( ))
        }
    }

    // fc_out mapping: 424 = 8*53 dots; thread t<212 does idx t and t+212
    const bool fcact = (j < 212);
    int fr0 = 0, fc0 = 0, fr1 = 0, fc1 = 0;
    float fb0 = 0, fb1 = 0;
    if (fcact) {
        fr0 = j / kO; fc0 = j - fr0 * kO;
        int i1 = j + 212;
        fr1 = i1 / kO; fc1 = i1 - fr1 * kO;
        fb0 = fcob[fc0]; fb1 = fcob[fc1];
    }
    __syncthreads();

    for (int t = 0; t < kT; ++t) {
        // ---------- Layer 1: hw1 = h1 @ Whh1^T ----------
        float a0[BTILE], a1[BTILE], a2[BTILE];
        #pragma unroll
        for (int r = 0; r < BTILE; ++r) { a0[r] = 0.f; a1[r] = 0.f; a2[r] = 0.f; }
        if (act) {
            const float* __restrict__ Wp = ws + WT_HH1 + j;
            for (int k = 0; k < kH; k += 4) {
                float wr[4], wz[4], wn[4];
                #pragma unroll
                for (int u = 0; u < 4; ++u) {
                    const float* p = Wp + (k + u) * kG;
                    wr[u] = p[0]; wz[u] = p[kH]; wn[u] = p[2 * kH];
                }
                #pragma unroll
                for (int r = 0; r < BTILE; ++r) {
                    const float4 hv4 = *reinterpret_cast<const float4*>(&h1s[r][k]);
                    const float hv[4] = {hv4.x, hv4.y, hv4.z, hv4.w};
                    #pragma unroll
                    for (int u = 0; u < 4; ++u) {
                        a0[r] = fmaf(wr[u], hv[u], a0[r]);
                        a1[r] = fmaf(wz[u], hv[u], a1[r]);
                        a2[r] = fmaf(wn[u], hv[u], a2[r]);
                    }
                }
            }
        }
        __syncthreads();
        if (act) {
            #pragma unroll
            for (int r = 0; r < BTILE; ++r) {
                float rr = sig_(xr[r] + a0[r]);
                float zz = sig_(xz[r] + a1[r]);
                float nn = tanh_(xn[r] + rr * (a2[r] + b1n));
                h1s[r][j] = (1.f - zz) * nn + zz * h1s[r][j];
            }
        }
        __syncthreads();

        // ---------- Layer 2: xw2 = h1@Wih2^T, hw2 = h2@Whh2^T ----------
        {
            float c0[BTILE], c1[BTILE], cx[BTILE], chn[BTILE];
            #pragma unroll
            for (int r = 0; r < BTILE; ++r) { c0[r]=0.f; c1[r]=0.f; cx[r]=0.f; chn[r]=0.f; }
            if (act) {
                const float* __restrict__ Wi = ws + WT_IH2 + j;
                const float* __restrict__ Wh = ws + WT_HH2 + j;
                for (int k = 0; k < kH; k += 4) {
                    float wri[4], wzi[4], wni[4], wrh[4], wzh[4], wnh[4];
                    #pragma unroll
                    for (int u = 0; u < 4; ++u) {
                        const float* pi = Wi + (k + u) * kG;
                        const float* ph = Wh + (k + u) * kG;
                        wri[u] = pi[0]; wzi[u] = pi[kH]; wni[u] = pi[2 * kH];
                        wrh[u] = ph[0]; wzh[u] = ph[kH]; wnh[u] = ph[2 * kH];
                    }
                    #pragma unroll
                    for (int r = 0; r < BTILE; ++r) {
                        const float4 xv4 = *reinterpret_cast<const float4*>(&h1s[r][k]);
                        const float4 hv4 = *reinterpret_cast<const float4*>(&h2s[r][k]);
                        const float xv[4] = {xv4.x, xv4.y, xv4.z, xv4.w};
                        const float hv[4] = {hv4.x, hv4.y, hv4.z, hv4.w};
                        #pragma unroll
                        for (int u = 0; u < 4; ++u) {
                            c0[r] = fmaf(wri[u], xv[u], c0[r]);
                            c0[r] = fmaf(wrh[u], hv[u], c0[r]);
                            c1[r] = fmaf(wzi[u], xv[u], c1[r]);
                            c1[r] = fmaf(wzh[u], hv[u], c1[r]);
                            cx[r] = fmaf(wni[u], xv[u], cx[r]);
                            chn[r] = fmaf(wnh[u], hv[u], chn[r]);
                        }
                    }
                }
            }
            __syncthreads();
            if (act) {
                #pragma unroll
                for (int r = 0; r < BTILE; ++r) {
                    float rr = sig_(c0[r] + b2r);
                    float zz = sig_(c1[r] + b2z);
                    float nn = tanh_(cx[r] + b2xn + rr * (chn[r] + b2hn));
                    h2s[r][j] = (1.f - zz) * nn + zz * h2s[r][j];
                }
            }
            __syncthreads();
        }

        // ---------- Layer 3 ----------
        {
            float c0[BTILE], c1[BTILE], cx[BTILE], chn[BTILE];
            #pragma unroll
            for (int r = 0; r < BTILE; ++r) { c0[r]=0.f; c1[r]=0.f; cx[r]=0.f; chn[r]=0.f; }
            if (act) {
                const float* __restrict__ Wi = ws + WT_IH3 + j;
                const float* __restrict__ Wh = ws + WT_HH3 + j;
                for (int k = 0; k < kH; k += 4) {
                    float wri[4], wzi[4], wni[4], wrh[4], wzh[4], wnh[4];
                    #pragma unroll
                    for (int u = 0; u < 4; ++u) {
                        const float* pi = Wi + (k + u) * kG;
                        const float* ph = Wh + (k + u) * kG;
                        wri[u] = pi[0]; wzi[u] = pi[kH]; wni[u] = pi[2 * kH];
                        wrh[u] = ph[0]; wzh[u] = ph[kH]; wnh[u] = ph[2 * kH];
                    }
                    #pragma unroll
                    for (int r = 0; r < BTILE; ++r) {
                        const float4 xv4 = *reinterpret_cast<const float4*>(&h2s[r][k]);
                        const float4 hv4 = *reinterpret_cast<const float4*>(&h3s[r][k]);
                        const float xv[4] = {xv4.x, xv4.y, xv4.z, xv4.w};
                        const float hv[4] = {hv4.x, hv4.y, hv4.z, hv4.w};
                        #pragma unroll
                        for (int u = 0; u < 4; ++u) {
                            c0[r] = fmaf(wri[u], xv[u], c0[r]);
                            c0[r] = fmaf(wrh[u], hv[u], c0[r]);
                            c1[r] = fmaf(wzi[u], xv[u], c1[r]);
                            c1[r] = fmaf(wzh[u], hv[u], c1[r]);
                            cx[r] = fmaf(wni[u], xv[u], cx[r]);
                            chn[r] = fmaf(wnh[u], hv[u], chn[r]);
                        }
                    }
                }
            }
            __syncthreads();
            if (act) {
                #pragma unroll
                for (int r = 0; r < BTILE; ++r) {
                    float rr = sig_(c0[r] + b3r);
                    float zz = sig_(c1[r] + b3z);
                    float nn = tanh_(cx[r] + b3xn + rr * (chn[r] + b3hn));
                    h3s[r][j] = (1.f - zz) * nn + zz * h3s[r][j];
                }
            }
            __syncthreads();
        }

        // ---------- Output head: sigmoid(h3 @ fc_out^T + b) (relu is no-op) ----------
        if (fcact) {
            float s0 = fb0, s1 = fb1;
            const float* w0 = fcoW + fc0 * kH;
            const float* w1 = fcoW + fc1 * kH;
            for (int k = 0; k < kH; k += 4) {
                const float4 wa = *reinterpret_cast<const float4*>(&w0[k]);
                const float4 ha = *reinterpret_cast<const float4*>(&h3s[fr0][k]);
                s0 = fmaf(wa.x, ha.x, s0); s0 = fmaf(wa.y, ha.y, s0);
                s0 = fmaf(wa.z, ha.z, s0); s0 = fmaf(wa.w, ha.w, s0);
                const float4 wb = *reinterpret_cast<const float4*>(&w1[k]);
                const float4 hb = *reinterpret_cast<const float4*>(&h3s[fr1][k]);
                s1 = fmaf(wb.x, hb.x, s1); s1 = fmaf(wb.y, hb.y, s1);
                s1 = fmaf(wb.z, hb.z, s1); s1 = fmaf(wb.w, hb.w, s1);
            }
            out[(b0 + fr0) * (kT * kO) + t * kO + fc0] = sig_(s0);
            out[(b0 + fr1) * (kT * kO) + t * kO + fc1] = sig_(s1);
        }
        // no barrier needed: next phase that WRITES any h is preceded by one
    }

    if (act) {
        #pragma unroll
        for (int r = 0; r < BTILE; ++r) {
            int b = b0 + r;
            out[OH1 + b * kH + j] = h1s[r][j];
            out[OH2 + b * kH + j] = h2s[r][j];
            out[OH3 + b * kH + j] = h3s[r][j];
        }
    }
}

extern "C" void kernel_launch(void* const* d_in, const int* in_sizes, int n_in,
                              void* d_out, int out_size, void* d_ws, size_t ws_size,
                              hipStream_t stream) {
    (void)in_sizes; (void)n_in; (void)out_size; (void)ws_size;
    const float* enc  = (const float*)d_in[0];
    const float* h1in = (const float*)d_in[1];
    const float* h2in = (const float*)d_in[2];
    const float* h3in = (const float*)d_in[3];
    const float* bn_g = (const float*)d_in[4];
    const float* bn_b = (const float*)d_in[5];
    const float* bn_m = (const float*)d_in[6];
    const float* bn_v = (const float*)d_in[7];
    const float* fciW = (const float*)d_in[8];
    const float* fcib = (const float*)d_in[9];
    const float* Wih1 = (const float*)d_in[10];
    const float* Whh1 = (const float*)d_in[11];
    const float* bih1 = (const float*)d_in[12];
    const float* bhh1 = (const float*)d_in[13];
    const float* Wih2 = (const float*)d_in[14];
    const float* Whh2 = (const float*)d_in[15];
    const float* bih2 = (const float*)d_in[16];
    const float* bhh2 = (const float*)d_in[17];
    const float* Wih3 = (const float*)d_in[18];
    const float* Whh3 = (const float*)d_in[19];
    const float* bih3 = (const float*)d_in[20];
    const float* bhh3 = (const float*)d_in[21];
    const float* fcoW = (const float*)d_in[22];
    const float* fcob = (const float*)d_in[23];
    float* ws  = (float*)d_ws;
    float* out = (float*)d_out;

    hipLaunchKernelGGL(prep_transpose, dim3((760000 + 255) / 256), dim3(256), 0, stream,
                       Whh1, Wih2, Whh2, Wih3, Whh3, Wih1, fciW, ws);
    hipLaunchKernelGGL(prep_input, dim3(kB), dim3(256), 0, stream,
                       enc, bn_g, bn_b, bn_m, bn_v, fcib, bih1, ws);
    hipLaunchKernelGGL(gru_main, dim3(NWG), dim3(256), 0, stream,
                       ws, h1in, h2in, h3in, bhh1, bih2, bhh2, bih3, bhh3, fcoW, fcob, out);
}

// Round 2
// 1406.871 us; speedup vs baseline: 4.9296x; 4.9296x over previous
//
#include <hip/hip_runtime.h>

typedef _Float16 half8 __attribute__((ext_vector_type(8)));
typedef float f32x4 __attribute__((ext_vector_type(4)));

namespace {
constexpr int kB = 2048;
constexpr int kT = 72;
constexpr int kI = 200;
constexpr int kH = 200;
constexpr int kO = 53;
constexpr int kG = 600;      // 3*kH
constexpr int BT = 16;       // batch rows per WG
constexpr int NWG = kB / BT; // 128
constexpr int MT = 38;       // M tiles of 16 covering 608 (600 padded)
constexpr int KS = 7;        // K slices of 32 covering 224 (200 padded)
constexpr int GSTR = 17;     // LDS G row stride (conflict-free)

// ws layout (float offsets)
constexpr int XW1    = 0;          // [2048][600] emb@Wih1^T + bih1
constexpr int WIH1T  = 1228800;    // [200][600] Wih1 transposed (prep only)
constexpr int FCINT  = 1348800;    // [200][200] fc_in_W transposed (prep only)
constexpr int F0     = 1388800;    // fp16 A-frags: hh1, ih2, hh2, ih3, hh3
constexpr int FSZ    = 68096;      // f32-equiv per frag matrix (38*7*64*8 halfs)
constexpr int FHEAD  = F0 + 5 * FSZ; // fc_out frags (4 tiles)
constexpr int PERM   = MT * KS * 64; // 17024 lane-rows per matrix

// output offsets (floats)
constexpr int OH1 = kB * kT * kO;  // 7815168
constexpr int OH2 = OH1 + kB * kH;
constexpr int OH3 = OH2 + kB * kH;
}

__device__ __forceinline__ float sig_(float x) { return 1.0f / (1.0f + __expf(-x)); }
__device__ __forceinline__ float tanh_(float x) {
    return 1.0f - 2.0f / (__expf(2.0f * x) + 1.0f);
}

// h master (fp32) + fp16 fragment-order shadow copy write
__device__ __forceinline__ void store_h(float* hm, _Float16* fb, int n, int j, float v) {
    hm[n * kH + j] = v;
    int ks = j >> 5, r = j & 31, lbb = r >> 3, jj = r & 7;
    fb[(ks * 64 + lbb * 16 + n) * 8 + jj] = (_Float16)v;
}

// ---------------- prep kernels ----------------

__global__ __launch_bounds__(256) void prep_transpose2(
    const float* __restrict__ Wih1, const float* __restrict__ fciW,
    float* __restrict__ ws) {
    int idx = blockIdx.x * 256 + threadIdx.x;
    if (idx < 120000) {
        int k = idx / kG, c = idx - k * kG;
        ws[WIH1T + idx] = Wih1[c * kI + k];
    } else {
        int i = idx - 120000;
        if (i < 40000) {
            int k = i / kH, h = i - k * kH;
            ws[FCINT + i] = fciW[h * kI + k];
        }
    }
}

// pack fp16 MFMA A-fragments: frag[mt][ks][lane][8], elem j -> W[mt*16+(lane&15)][ks*32+(lane>>4)*8+j]
__global__ __launch_bounds__(256) void prep_frags(
    const float* __restrict__ Whh1, const float* __restrict__ Wih2,
    const float* __restrict__ Whh2, const float* __restrict__ Wih3,
    const float* __restrict__ Whh3, const float* __restrict__ fcoW,
    float* __restrict__ ws) {
    int idx = blockIdx.x * 256 + threadIdx.x;
    const float* src; int R; long long dstHalf; int rem;
    if (idx < 5 * PERM) {
        int m = idx / PERM; rem = idx - m * PERM;
        switch (m) {
            case 0: src = Whh1; break;
            case 1: src = Wih2; break;
            case 2: src = Whh2; break;
            case 3: src = Wih3; break;
            default: src = Whh3; break;
        }
        R = kG; dstHalf = 2LL * (F0 + m * FSZ);
    } else {
        rem = idx - 5 * PERM;
        if (rem >= 4 * KS * 64) return;
        src = fcoW; R = kO; dstHalf = 2LL * FHEAD;
    }
    int lane = rem & 63;
    int tmp = rem >> 6;
    int ks = tmp % KS;
    int mt = tmp / KS;
    int row = mt * 16 + (lane & 15);
    int k0 = ks * 32 + (lane >> 4) * 8;
    half8 v;
    #pragma unroll
    for (int j = 0; j < 8; ++j) {
        int k = k0 + j;
        v[j] = (_Float16)((row < R && k < kH) ? src[row * kH + k] : 0.0f);
    }
    *(half8*)((_Float16*)ws + dstHalf + (long long)rem * 8) = v;
}

// One block per batch row: BN -> fc_in+ReLU -> xw1 = emb@Wih1^T + bih1
__global__ __launch_bounds__(256) void prep_input(
    const float* __restrict__ enc,
    const float* __restrict__ bn_g, const float* __restrict__ bn_b,
    const float* __restrict__ bn_m, const float* __restrict__ bn_v,
    const float* __restrict__ fcib, const float* __restrict__ bih1,
    float* ws) {
    __shared__ float xh[kI];
    __shared__ float emb[kH];
    const int b = blockIdx.x, tid = threadIdx.x;
    const float* fcInT = ws + FCINT;
    const float* Wih1T = ws + WIH1T;
    if (tid < kI) {
        float x = enc[b * kI + tid];
        xh[tid] = (x - bn_m[tid]) * rsqrtf(bn_v[tid] + 1e-5f) * bn_g[tid] + bn_b[tid];
    }
    __syncthreads();
    if (tid < kH) {
        float s = fcib[tid];
        for (int k = 0; k < kI; ++k) s = fmaf(xh[k], fcInT[k * kH + tid], s);
        emb[tid] = fmaxf(s, 0.0f);
    }
    __syncthreads();
    for (int c = tid; c < kG; c += 256) {
        float s = bih1[c];
        for (int k = 0; k < kH; ++k) s = fmaf(emb[k], Wih1T[k * kG + c], s);
        ws[XW1 + b * kG + c] = s;
    }
}

// ---------------- main persistent GRU kernel ----------------
// 128 WGs x 512 threads (8 waves). WG owns 16 batch rows. MFMA 16x16x32 f16.
__global__ __launch_bounds__(512, 2) void gru_main(
    const float* __restrict__ ws,
    const float* __restrict__ h1in, const float* __restrict__ h2in,
    const float* __restrict__ h3in,
    const float* __restrict__ bhh1,
    const float* __restrict__ bih2, const float* __restrict__ bhh2,
    const float* __restrict__ bih3, const float* __restrict__ bhh3,
    const float* __restrict__ fcob,
    float* __restrict__ out) {
    __shared__ float h1m[BT * kH], h2m[BT * kH], h3m[BT * kH];
    __shared__ __align__(16) _Float16 fb1[KS * 64 * 8];
    __shared__ __align__(16) _Float16 fb2[KS * 64 * 8];
    __shared__ __align__(16) _Float16 fb3[KS * 64 * 8];
    __shared__ float Gs[608 * GSTR];
    __shared__ float Gns[208 * GSTR];
    __shared__ float bias[12 * kH];
    __shared__ float hb[64];

    const int tid = threadIdx.x, wv = tid >> 6, ln = tid & 63;
    const int lb = ln >> 4, lr = ln & 15;
    const int b0 = blockIdx.x * BT;

    // ---- init: h states (fp32 master + fp16 frag shadow), frag K-pad zeros, biases
    for (int idx = tid; idx < BT * kH; idx += 512) {
        int n = idx / kH, j = idx - n * kH;
        store_h(h1m, fb1, n, j, h1in[(b0 + n) * kH + j]);
        store_h(h2m, fb2, n, j, h2in[(b0 + n) * kH + j]);
        store_h(h3m, fb3, n, j, h3in[(b0 + n) * kH + j]);
    }
    for (int idx = tid; idx < 3 * 48 * 8; idx += 512) {  // ks=6, slots r=8..31 (k=200..223)
        int w = idx / 384, r = idx - w * 384;
        int lane = 16 + r / 8, jj = r & 7;
        _Float16* f = (w == 0) ? fb1 : (w == 1) ? fb2 : fb3;
        f[(6 * 64 + lane) * 8 + jj] = (_Float16)0.0f;
    }
    for (int idx = tid; idx < 12 * kH; idx += 512) {
        int c = idx / kH, j = idx - c * kH;
        float v;
        switch (c) {
            case 0:  v = bhh1[j]; break;
            case 1:  v = bhh1[kH + j]; break;
            case 2:  v = 0.0f; break;
            case 3:  v = bhh1[2 * kH + j]; break;
            case 4:  v = bih2[j] + bhh2[j]; break;
            case 5:  v = bih2[kH + j] + bhh2[kH + j]; break;
            case 6:  v = bih2[2 * kH + j]; break;
            case 7:  v = bhh2[2 * kH + j]; break;
            case 8:  v = bih3[j] + bhh3[j]; break;
            case 9:  v = bih3[kH + j] + bhh3[kH + j]; break;
            case 10: v = bih3[2 * kH + j]; break;
            default: v = bhh3[2 * kH + j]; break;
        }
        bias[idx] = v;
    }
    if (tid < 64) hb[tid] = (tid < kO) ? fcob[tid] : 0.0f;
    __syncthreads();

    const half8* WFhh1 = (const half8*)(ws + F0);
    const half8* WFih2 = (const half8*)(ws + F0 + FSZ);
    const half8* WFhh2 = (const half8*)(ws + F0 + 2 * FSZ);
    const half8* WFih3 = (const half8*)(ws + F0 + 3 * FSZ);
    const half8* WFhh3 = (const half8*)(ws + F0 + 4 * FSZ);
    const half8* WFhead = (const half8*)(ws + FHEAD);

    for (int t = 0; t < kT; ++t) {
        // ---------- Layer 1 matmul: G = Whh1 x h1 ----------
        {
            half8 bf[KS];
            #pragma unroll
            for (int ks = 0; ks < KS; ++ks)
                bf[ks] = *(const half8*)(fb1 + (ks * 64 + ln) * 8);
            for (int mt = wv; mt < MT; mt += 8) {
                const half8* wp = WFhh1 + (mt * KS) * 64 + ln;
                f32x4 acc = {0.f, 0.f, 0.f, 0.f};
                #pragma unroll
                for (int ks = 0; ks < KS; ++ks)
                    acc = __builtin_amdgcn_mfma_f32_16x16x32_f16(wp[ks * 64], bf[ks], acc, 0, 0, 0);
                int row = mt * 16 + lb * 4;
                #pragma unroll
                for (int rg = 0; rg < 4; ++rg) Gs[(row + rg) * GSTR + lr] = acc[rg];
            }
        }
        __syncthreads();
        // ---------- update h1 ----------
        for (int idx = tid; idx < BT * kH; idx += 512) {
            int n = idx / kH, j = idx - n * kH;
            const float* xw = ws + XW1 + (b0 + n) * kG;
            float r  = sig_(xw[j]          + bias[j]          + Gs[j * GSTR + n]);
            float z  = sig_(xw[kH + j]     + bias[kH + j]     + Gs[(kH + j) * GSTR + n]);
            float nn = tanh_(xw[2 * kH + j] + r * (Gs[(2 * kH + j) * GSTR + n] + bias[3 * kH + j]));
            float h = h1m[idx];
            store_h(h1m, fb1, n, j, (1.0f - z) * nn + z * h);
        }
        __syncthreads();
        // ---------- Layer 2 matmul: G = h1@Wih2^T (+ h2@Whh2^T for r,z), Gn = n-part of hh ----------
        {
            half8 bx[KS], bh[KS];
            #pragma unroll
            for (int ks = 0; ks < KS; ++ks) {
                bx[ks] = *(const half8*)(fb1 + (ks * 64 + ln) * 8);
                bh[ks] = *(const half8*)(fb2 + (ks * 64 + ln) * 8);
            }
            for (int mt = wv; mt < MT; mt += 8) {
                const half8* wpx = WFih2 + (mt * KS) * 64 + ln;
                const half8* wph = WFhh2 + (mt * KS) * 64 + ln;
                f32x4 ax = {0.f, 0.f, 0.f, 0.f}, ah = {0.f, 0.f, 0.f, 0.f};
                #pragma unroll
                for (int ks = 0; ks < KS; ++ks) {
                    ax = __builtin_amdgcn_mfma_f32_16x16x32_f16(wpx[ks * 64], bx[ks], ax, 0, 0, 0);
                    ah = __builtin_amdgcn_mfma_f32_16x16x32_f16(wph[ks * 64], bh[ks], ah, 0, 0, 0);
                }
                int row = mt * 16 + lb * 4;
                if (mt < 25) {
                    #pragma unroll
                    for (int rg = 0; rg < 4; ++rg) Gs[(row + rg) * GSTR + lr] = ax[rg] + ah[rg];
                } else {
                    #pragma unroll
                    for (int rg = 0; rg < 4; ++rg) {
                        Gs[(row + rg) * GSTR + lr] = ax[rg];
                        Gns[(row - 400 + rg) * GSTR + lr] = ah[rg];
                    }
                }
            }
        }
        __syncthreads();
        // ---------- update h2 ----------
        for (int idx = tid; idx < BT * kH; idx += 512) {
            int n = idx / kH, j = idx - n * kH;
            float r  = sig_(Gs[j * GSTR + n]          + bias[4 * kH + j]);
            float z  = sig_(Gs[(kH + j) * GSTR + n]   + bias[5 * kH + j]);
            float nn = tanh_(Gs[(2 * kH + j) * GSTR + n] + bias[6 * kH + j]
                             + r * (Gns[j * GSTR + n] + bias[7 * kH + j]));
            float h = h2m[idx];
            store_h(h2m, fb2, n, j, (1.0f - z) * nn + z * h);
        }
        __syncthreads();
        // ---------- Layer 3 matmul ----------
        {
            half8 bx[KS], bh[KS];
            #pragma unroll
            for (int ks = 0; ks < KS; ++ks) {
                bx[ks] = *(const half8*)(fb2 + (ks * 64 + ln) * 8);
                bh[ks] = *(const half8*)(fb3 + (ks * 64 + ln) * 8);
            }
            for (int mt = wv; mt < MT; mt += 8) {
                const half8* wpx = WFih3 + (mt * KS) * 64 + ln;
                const half8* wph = WFhh3 + (mt * KS) * 64 + ln;
                f32x4 ax = {0.f, 0.f, 0.f, 0.f}, ah = {0.f, 0.f, 0.f, 0.f};
                #pragma unroll
                for (int ks = 0; ks < KS; ++ks) {
                    ax = __builtin_amdgcn_mfma_f32_16x16x32_f16(wpx[ks * 64], bx[ks], ax, 0, 0, 0);
                    ah = __builtin_amdgcn_mfma_f32_16x16x32_f16(wph[ks * 64], bh[ks], ah, 0, 0, 0);
                }
                int row = mt * 16 + lb * 4;
                if (mt < 25) {
                    #pragma unroll
                    for (int rg = 0; rg < 4; ++rg) Gs[(row + rg) * GSTR + lr] = ax[rg] + ah[rg];
                } else {
                    #pragma unroll
                    for (int rg = 0; rg < 4; ++rg) {
                        Gs[(row + rg) * GSTR + lr] = ax[rg];
                        Gns[(row - 400 + rg) * GSTR + lr] = ah[rg];
                    }
                }
            }
        }
        __syncthreads();
        // ---------- update h3 ----------
        for (int idx = tid; idx < BT * kH; idx += 512) {
            int n = idx / kH, j = idx - n * kH;
            float r  = sig_(Gs[j * GSTR + n]          + bias[8 * kH + j]);
            float z  = sig_(Gs[(kH + j) * GSTR + n]   + bias[9 * kH + j]);
            float nn = tanh_(Gs[(2 * kH + j) * GSTR + n] + bias[10 * kH + j]
                             + r * (Gns[j * GSTR + n] + bias[11 * kH + j]));
            float h = h3m[idx];
            store_h(h3m, fb3, n, j, (1.0f - z) * nn + z * h);
        }
        __syncthreads();
        // ---------- output head: sigmoid(h3 @ fc_out^T + b) (waves 0..3) ----------
        if (wv < 4) {
            half8 b3[KS];
            #pragma unroll
            for (int ks = 0; ks < KS; ++ks)
                b3[ks] = *(const half8*)(fb3 + (ks * 64 + ln) * 8);
            const half8* wp = WFhead + (wv * KS) * 64 + ln;
            f32x4 acc = {0.f, 0.f, 0.f, 0.f};
            #pragma unroll
            for (int ks = 0; ks < KS; ++ks)
                acc = __builtin_amdgcn_mfma_f32_16x16x32_f16(wp[ks * 64], b3[ks], acc, 0, 0, 0);
            int o0 = wv * 16 + lb * 4;
            int obase = (b0 + lr) * (kT * kO) + t * kO;
            #pragma unroll
            for (int rg = 0; rg < 4; ++rg) {
                int o = o0 + rg;
                if (o < kO) out[obase + o] = sig_(acc[rg] + hb[o]);
            }
        }
        // no extra barrier: next phase writing Gs is after the post-L1 barrier,
        // and nothing before it conflicts with the head's fb3/h3 reads.
    }

    // final hidden states
    for (int idx = tid; idx < BT * kH; idx += 512) {
        int n = idx / kH, j = idx - n * kH;
        out[OH1 + (b0 + n) * kH + j] = h1m[idx];
        out[OH2 + (b0 + n) * kH + j] = h2m[idx];
        out[OH3 + (b0 + n) * kH + j] = h3m[idx];
    }
}

extern "C" void kernel_launch(void* const* d_in, const int* in_sizes, int n_in,
                              void* d_out, int out_size, void* d_ws, size_t ws_size,
                              hipStream_t stream) {
    (void)in_sizes; (void)n_in; (void)out_size; (void)ws_size;
    const float* enc  = (const float*)d_in[0];
    const float* h1in = (const float*)d_in[1];
    const float* h2in = (const float*)d_in[2];
    const float* h3in = (const float*)d_in[3];
    const float* bn_g = (const float*)d_in[4];
    const float* bn_b = (const float*)d_in[5];
    const float* bn_m = (const float*)d_in[6];
    const float* bn_v = (const float*)d_in[7];
    const float* fciW = (const float*)d_in[8];
    const float* fcib = (const float*)d_in[9];
    const float* Wih1 = (const float*)d_in[10];
    const float* Whh1 = (const float*)d_in[11];
    const float* bih1 = (const float*)d_in[12];
    const float* bhh1 = (const float*)d_in[13];
    const float* Wih2 = (const float*)d_in[14];
    const float* Whh2 = (const float*)d_in[15];
    const float* bih2 = (const float*)d_in[16];
    const float* bhh2 = (const float*)d_in[17];
    const float* Wih3 = (const float*)d_in[18];
    const float* Whh3 = (const float*)d_in[19];
    const float* bih3 = (const float*)d_in[20];
    const float* bhh3 = (const float*)d_in[21];
    const float* fcoW = (const float*)d_in[22];
    const float* fcob = (const float*)d_in[23];
    float* ws  = (float*)d_ws;
    float* out = (float*)d_out;

    hipLaunchKernelGGL(prep_transpose2, dim3(625), dim3(256), 0, stream, Wih1, fciW, ws);
    hipLaunchKernelGGL(prep_frags, dim3(340), dim3(256), 0, stream,
                       Whh1, Wih2, Whh2, Wih3, Whh3, fcoW, ws);
    hipLaunchKernelGGL(prep_input, dim3(kB), dim3(256), 0, stream,
                       enc, bn_g, bn_b, bn_m, bn_v, fcib, bih1, ws);
    hipLaunchKernelGGL(gru_main, dim3(NWG), dim3(512), 0, stream,
                       ws, h1in, h2in, h3in, bhh1, bih2, bhh2, bih3, bhh3, fcob, out);
}

// Round 4
// 1394.210 us; speedup vs baseline: 4.9743x; 1.0091x over previous
//
#include <hip/hip_runtime.h>

typedef _Float16 half8 __attribute__((ext_vector_type(8)));
typedef float f32x4 __attribute__((ext_vector_type(4)));

namespace {
constexpr int kB = 2048;
constexpr int kT = 72;
constexpr int kI = 200;
constexpr int kH = 200;
constexpr int kO = 53;
constexpr int kG = 600;      // 3*kH
constexpr int BT = 16;       // batch rows per WG
constexpr int NWG = kB / BT; // 128
constexpr int MT = 38;       // M tiles of 16 covering 608 (600 padded)
constexpr int KS = 7;        // K slices of 32 covering 224 (200 padded)
constexpr int GSTR = 18;     // LDS G col stride: writes exactly 2-way (free)

// ws layout (float offsets)
constexpr int XW1    = 0;          // [2048][600] emb@Wih1^T + bih1
constexpr int WIH1T  = 1228800;    // [200][600] Wih1 transposed (prep only)
constexpr int FCINT  = 1348800;    // [200][200] fc_in_W transposed (prep only)
constexpr int F0     = 1388800;    // fp16 A-frags: hh1, ih2, hh2, ih3, hh3
constexpr int FSZ    = 68096;      // f32-equiv per frag matrix (38*7*64*8 halfs)
constexpr int FHEAD  = F0 + 5 * FSZ; // fc_out frags (4 tiles)
constexpr int PERM   = MT * KS * 64; // 17024 lane-rows per matrix

// output offsets (floats)
constexpr int OH1 = kB * kT * kO;  // 7815168
constexpr int OH2 = OH1 + kB * kH;
constexpr int OH3 = OH2 + kB * kH;
}

__device__ __forceinline__ float sig_(float x) { return 1.0f / (1.0f + __expf(-x)); }
__device__ __forceinline__ float tanh_(float x) {
    return 1.0f - 2.0f / (__expf(2.0f * x) + 1.0f);
}

// fp16 fragment-order shadow write of h element (n, j)
__device__ __forceinline__ void store_fb(_Float16* fb, int n, int j, float v) {
    int ks = j >> 5, r = j & 31;
    fb[((ks << 6) + ((r >> 3) << 4) + n) * 8 + (r & 7)] = (_Float16)v;
}

// ---------------- prep kernels ----------------

__global__ __launch_bounds__(256) void prep_transpose2(
    const float* __restrict__ Wih1, const float* __restrict__ fciW,
    float* __restrict__ ws) {
    int idx = blockIdx.x * 256 + threadIdx.x;
    if (idx < 120000) {
        int k = idx / kG, c = idx - k * kG;
        ws[WIH1T + idx] = Wih1[c * kI + k];
    } else {
        int i = idx - 120000;
        if (i < 40000) {
            int k = i / kH, h = i - k * kH;
            ws[FCINT + i] = fciW[h * kI + k];
        }
    }
}

// pack fp16 MFMA A-fragments: frag[mt][ks][lane][8], elem j -> W[mt*16+(lane&15)][ks*32+(lane>>4)*8+j]
__global__ __launch_bounds__(256) void prep_frags(
    const float* __restrict__ Whh1, const float* __restrict__ Wih2,
    const float* __restrict__ Whh2, const float* __restrict__ Wih3,
    const float* __restrict__ Whh3, const float* __restrict__ fcoW,
    float* __restrict__ ws) {
    int idx = blockIdx.x * 256 + threadIdx.x;
    const float* src; int R; long long dstHalf; int rem;
    if (idx < 5 * PERM) {
        int m = idx / PERM; rem = idx - m * PERM;
        switch (m) {
            case 0: src = Whh1; break;
            case 1: src = Wih2; break;
            case 2: src = Whh2; break;
            case 3: src = Wih3; break;
            default: src = Whh3; break;
        }
        R = kG; dstHalf = 2LL * (F0 + m * FSZ);
    } else {
        rem = idx - 5 * PERM;
        if (rem >= 4 * KS * 64) return;
        src = fcoW; R = kO; dstHalf = 2LL * FHEAD;
    }
    int lane = rem & 63;
    int tmp = rem >> 6;
    int ks = tmp % KS;
    int mt = tmp / KS;
    int row = mt * 16 + (lane & 15);
    int k0 = ks * 32 + (lane >> 4) * 8;
    half8 v;
    #pragma unroll
    for (int j = 0; j < 8; ++j) {
        int k = k0 + j;
        v[j] = (_Float16)((row < R && k < kH) ? src[row * kH + k] : 0.0f);
    }
    *(half8*)((_Float16*)ws + dstHalf + (long long)rem * 8) = v;
}

// One block per batch row: BN -> fc_in+ReLU -> xw1 = emb@Wih1^T + bih1
__global__ __launch_bounds__(256) void prep_input(
    const float* __restrict__ enc,
    const float* __restrict__ bn_g, const float* __restrict__ bn_b,
    const float* __restrict__ bn_m, const float* __restrict__ bn_v,
    const float* __restrict__ fcib, const float* __restrict__ bih1,
    float* ws) {
    __shared__ float xh[kI];
    __shared__ float emb[kH];
    const int b = blockIdx.x, tid = threadIdx.x;
    const float* fcInT = ws + FCINT;
    const float* Wih1T = ws + WIH1T;
    if (tid < kI) {
        float x = enc[b * kI + tid];
        xh[tid] = (x - bn_m[tid]) * rsqrtf(bn_v[tid] + 1e-5f) * bn_g[tid] + bn_b[tid];
    }
    __syncthreads();
    if (tid < kH) {
        float s = fcib[tid];
        for (int k = 0; k < kI; ++k) s = fmaf(xh[k], fcInT[k * kH + tid], s);
        emb[tid] = fmaxf(s, 0.0f);
    }
    __syncthreads();
    for (int c = tid; c < kG; c += 256) {
        float s = bih1[c];
        for (int k = 0; k < kH; ++k) s = fmaf(emb[k], Wih1T[k * kG + c], s);
        ws[XW1 + b * kG + c] = s;
    }
}

// ---------------- main persistent GRU kernel ----------------
// 128 WGs x 1024 threads (16 waves). WG owns 16 batch rows. MFMA 16x16x32 f16.
// h states live in registers (thread (tid,s) owns (n=tid&15, j=(tid>>4)+s*64)).
// STRICT barrier structure: every phase is barrier-delimited (no overlap).
__global__ __launch_bounds__(1024, 4) void gru_main(
    const float* __restrict__ ws,
    const float* __restrict__ h1in, const float* __restrict__ h2in,
    const float* __restrict__ h3in,
    const float* __restrict__ bhh1,
    const float* __restrict__ bih2, const float* __restrict__ bhh2,
    const float* __restrict__ bih3, const float* __restrict__ bhh3,
    const float* __restrict__ fcob,
    float* __restrict__ out) {
    __shared__ float xwL[kG * BT];                         // 38400 B, [j][n]
    __shared__ __align__(16) _Float16 fb1[KS * 64 * 8];    // 7168 B each
    __shared__ __align__(16) _Float16 fb2[KS * 64 * 8];
    __shared__ __align__(16) _Float16 fb3[KS * 64 * 8];
    __shared__ float Gs[608 * GSTR];                       // 43776 B
    __shared__ float Gns[208 * GSTR];                      // 14976 B
    __shared__ float bias[9 * kH];                         // 7200 B
    __shared__ float hb[64];

    const int tid = threadIdx.x, wv = tid >> 6, ln = tid & 63;
    const int lb = ln >> 4, lr = ln & 15;
    const int b0 = blockIdx.x * BT;

    // ---- stage xw1 (time-invariant) into LDS, folding bhh1 r/z biases
    for (int i = tid; i < kG * BT; i += 1024) {
        int n = i / kG, j = i - n * kG;
        float v = ws[XW1 + (b0 + n) * kG + j];
        if (j < 2 * kH) v += bhh1[j];
        xwL[j * BT + n] = v;
    }
    // ---- biases: [0]=b1n [1]=b2r [2]=b2z [3]=b2xn [4]=b2hn [5..8]=L3
    for (int i = tid; i < 9 * kH; i += 1024) {
        int c = i / kH, j = i - c * kH;
        float v;
        switch (c) {
            case 0:  v = bhh1[2 * kH + j]; break;
            case 1:  v = bih2[j] + bhh2[j]; break;
            case 2:  v = bih2[kH + j] + bhh2[kH + j]; break;
            case 3:  v = bih2[2 * kH + j]; break;
            case 4:  v = bhh2[2 * kH + j]; break;
            case 5:  v = bih3[j] + bhh3[j]; break;
            case 6:  v = bih3[kH + j] + bhh3[kH + j]; break;
            case 7:  v = bih3[2 * kH + j]; break;
            default: v = bhh3[2 * kH + j]; break;
        }
        bias[i] = v;
    }
    if (tid < 64) hb[tid] = (tid < kO) ? fcob[tid] : 0.0f;

    // ---- h states -> registers + fp16 frag shadows
    float h1r[4], h2r[4], h3r[4];
    #pragma unroll
    for (int s = 0; s < 4; ++s) {
        int idx = tid + s * 1024;
        if (idx < BT * kH) {
            int n = idx & 15, j = idx >> 4;
            h1r[s] = h1in[(b0 + n) * kH + j];
            h2r[s] = h2in[(b0 + n) * kH + j];
            h3r[s] = h3in[(b0 + n) * kH + j];
            store_fb(fb1, n, j, h1r[s]);
            store_fb(fb2, n, j, h2r[s]);
            store_fb(fb3, n, j, h3r[s]);
        } else { h1r[s] = h2r[s] = h3r[s] = 0.0f; }
    }
    // zero fp16 K-pad (ks=6, k=200..223 -> frag slots lane 16..63)
    for (int i = tid; i < 3 * 48 * 8; i += 1024) {
        int w = i / 384, r = i - w * 384;
        int lane = 16 + (r >> 3), jj = r & 7;
        _Float16* f = (w == 0) ? fb1 : (w == 1) ? fb2 : fb3;
        f[(6 * 64 + lane) * 8 + jj] = (_Float16)0.0f;
    }
    __syncthreads();

    const half8* WFhh1 = (const half8*)(ws + F0);
    const half8* WFih2 = (const half8*)(ws + F0 + FSZ);
    const half8* WFhh2 = (const half8*)(ws + F0 + 2 * FSZ);
    const half8* WFih3 = (const half8*)(ws + F0 + 3 * FSZ);
    const half8* WFhh3 = (const half8*)(ws + F0 + 4 * FSZ);
    const half8* WFhead = (const half8*)(ws + FHEAD);

    for (int t = 0; t < kT; ++t) {
        // ---------- Layer 1 matmul: Gs = Whh1 x h1 ----------
        {
            half8 bf[KS];
            #pragma unroll
            for (int ks = 0; ks < KS; ++ks)
                bf[ks] = *(const half8*)(fb1 + (ks * 64 + ln) * 8);
            for (int mt = wv; mt < MT; mt += 16) {
                const half8* wp = WFhh1 + (mt * KS) * 64 + ln;
                f32x4 acc = {0.f, 0.f, 0.f, 0.f};
                #pragma unroll
                for (int ks = 0; ks < KS; ++ks)
                    acc = __builtin_amdgcn_mfma_f32_16x16x32_f16(wp[ks * 64], bf[ks], acc, 0, 0, 0);
                int row = mt * 16 + lb * 4;
                #pragma unroll
                for (int rg = 0; rg < 4; ++rg) Gs[(row + rg) * GSTR + lr] = acc[rg];
            }
        }
        __syncthreads();
        // ---------- update h1 ----------
        #pragma unroll
        for (int s = 0; s < 4; ++s) {
            int idx = tid + s * 1024;
            if (idx < BT * kH) {
                int n = idx & 15, j = idx >> 4;
                float r  = sig_(xwL[j * BT + n]            + Gs[j * GSTR + n]);
                float z  = sig_(xwL[(kH + j) * BT + n]     + Gs[(kH + j) * GSTR + n]);
                float nn = tanh_(xwL[(2 * kH + j) * BT + n] + r * (Gs[(2 * kH + j) * GSTR + n] + bias[j]));
                h1r[s] = (1.0f - z) * nn + z * h1r[s];
                store_fb(fb1, n, j, h1r[s]);
            }
        }
        __syncthreads();
        // ---------- Layer 2 matmul ----------
        {
            half8 bx[KS], bh[KS];
            #pragma unroll
            for (int ks = 0; ks < KS; ++ks) {
                bx[ks] = *(const half8*)(fb1 + (ks * 64 + ln) * 8);
                bh[ks] = *(const half8*)(fb2 + (ks * 64 + ln) * 8);
            }
            for (int mt = wv; mt < MT; mt += 16) {
                const half8* wpx = WFih2 + (mt * KS) * 64 + ln;
                const half8* wph = WFhh2 + (mt * KS) * 64 + ln;
                f32x4 ax = {0.f, 0.f, 0.f, 0.f}, ah = {0.f, 0.f, 0.f, 0.f};
                #pragma unroll
                for (int ks = 0; ks < KS; ++ks) {
                    ax = __builtin_amdgcn_mfma_f32_16x16x32_f16(wpx[ks * 64], bx[ks], ax, 0, 0, 0);
                    ah = __builtin_amdgcn_mfma_f32_16x16x32_f16(wph[ks * 64], bh[ks], ah, 0, 0, 0);
                }
                int row = mt * 16 + lb * 4;
                if (mt < 25) {
                    #pragma unroll
                    for (int rg = 0; rg < 4; ++rg) Gs[(row + rg) * GSTR + lr] = ax[rg] + ah[rg];
                } else {
                    #pragma unroll
                    for (int rg = 0; rg < 4; ++rg) {
                        Gs[(row + rg) * GSTR + lr] = ax[rg];
                        Gns[(row - 400 + rg) * GSTR + lr] = ah[rg];
                    }
                }
            }
        }
        __syncthreads();
        // ---------- update h2 ----------
        #pragma unroll
        for (int s = 0; s < 4; ++s) {
            int idx = tid + s * 1024;
            if (idx < BT * kH) {
                int n = idx & 15, j = idx >> 4;
                float r  = sig_(Gs[j * GSTR + n]            + bias[kH + j]);
                float z  = sig_(Gs[(kH + j) * GSTR + n]     + bias[2 * kH + j]);
                float nn = tanh_(Gs[(2 * kH + j) * GSTR + n] + bias[3 * kH + j]
                                 + r * (Gns[j * GSTR + n]   + bias[4 * kH + j]));
                h2r[s] = (1.0f - z) * nn + z * h2r[s];
                store_fb(fb2, n, j, h2r[s]);
            }
        }
        __syncthreads();
        // ---------- Layer 3 matmul ----------
        {
            half8 bx[KS], bh[KS];
            #pragma unroll
            for (int ks = 0; ks < KS; ++ks) {
                bx[ks] = *(const half8*)(fb2 + (ks * 64 + ln) * 8);
                bh[ks] = *(const half8*)(fb3 + (ks * 64 + ln) * 8);
            }
            for (int mt = wv; mt < MT; mt += 16) {
                const half8* wpx = WFih3 + (mt * KS) * 64 + ln;
                const half8* wph = WFhh3 + (mt * KS) * 64 + ln;
                f32x4 ax = {0.f, 0.f, 0.f, 0.f}, ah = {0.f, 0.f, 0.f, 0.f};
                #pragma unroll
                for (int ks = 0; ks < KS; ++ks) {
                    ax = __builtin_amdgcn_mfma_f32_16x16x32_f16(wpx[ks * 64], bx[ks], ax, 0, 0, 0);
                    ah = __builtin_amdgcn_mfma_f32_16x16x32_f16(wph[ks * 64], bh[ks], ah, 0, 0, 0);
                }
                int row = mt * 16 + lb * 4;
                if (mt < 25) {
                    #pragma unroll
                    for (int rg = 0; rg < 4; ++rg) Gs[(row + rg) * GSTR + lr] = ax[rg] + ah[rg];
                } else {
                    #pragma unroll
                    for (int rg = 0; rg < 4; ++rg) {
                        Gs[(row + rg) * GSTR + lr] = ax[rg];
                        Gns[(row - 400 + rg) * GSTR + lr] = ah[rg];
                    }
                }
            }
        }
        __syncthreads();
        // ---------- update h3 ----------
        #pragma unroll
        for (int s = 0; s < 4; ++s) {
            int idx = tid + s * 1024;
            if (idx < BT * kH) {
                int n = idx & 15, j = idx >> 4;
                float r  = sig_(Gs[j * GSTR + n]            + bias[5 * kH + j]);
                float z  = sig_(Gs[(kH + j) * GSTR + n]     + bias[6 * kH + j]);
                float nn = tanh_(Gs[(2 * kH + j) * GSTR + n] + bias[7 * kH + j]
                                 + r * (Gns[j * GSTR + n]   + bias[8 * kH + j]));
                h3r[s] = (1.0f - z) * nn + z * h3r[s];
                store_fb(fb3, n, j, h3r[s]);
            }
        }
        __syncthreads();
        // ---------- output head (waves 0..3): sigmoid(h3 @ fc_out^T + b) ----------
        if (wv < 4) {
            half8 b3[KS];
            #pragma unroll
            for (int ks = 0; ks < KS; ++ks)
                b3[ks] = *(const half8*)(fb3 + (ks * 64 + ln) * 8);
            const half8* wp = WFhead + (wv * KS) * 64 + ln;
            f32x4 acc = {0.f, 0.f, 0.f, 0.f};
            #pragma unroll
            for (int ks = 0; ks < KS; ++ks)
                acc = __builtin_amdgcn_mfma_f32_16x16x32_f16(wp[ks * 64], b3[ks], acc, 0, 0, 0);
            int o0 = wv * 16 + lb * 4;
            int obase = (b0 + lr) * (kT * kO) + t * kO;
            #pragma unroll
            for (int rg = 0; rg < 4; ++rg) {
                int o = o0 + rg;
                if (o < kO) out[obase + o] = sig_(acc[rg] + hb[o]);
            }
        }
        // STRICT: no cross-iteration overlap (was the prime suspect for the
        // post-timing divergence in R3). Cost: 72 barriers ≈ noise.
        __syncthreads();
    }

    // ---- final hidden states: stage in LDS (Gs) for coalesced global writes
    #pragma unroll
    for (int s = 0; s < 4; ++s) {
        int idx = tid + s * 1024;
        if (idx < BT * kH) {
            Gs[idx] = h1r[s];
            Gs[3200 + idx] = h2r[s];
            Gs[6400 + idx] = h3r[s];
        }
    }
    __syncthreads();
    for (int i = tid; i < BT * kH; i += 1024) {
        int n = i / kH, j = i - n * kH;
        int src = j * BT + n;
        out[OH1 + (b0 + n) * kH + j] = Gs[src];
        out[OH2 + (b0 + n) * kH + j] = Gs[3200 + src];
        out[OH3 + (b0 + n) * kH + j] = Gs[6400 + src];
    }
}

extern "C" void kernel_launch(void* const* d_in, const int* in_sizes, int n_in,
                              void* d_out, int out_size, void* d_ws, size_t ws_size,
                              hipStream_t stream) {
    (void)in_sizes; (void)n_in; (void)out_size; (void)ws_size;
    const float* enc  = (const float*)d_in[0];
    const float* h1in = (const float*)d_in[1];
    const float* h2in = (const float*)d_in[2];
    const float* h3in = (const float*)d_in[3];
    const float* bn_g = (const float*)d_in[4];
    const float* bn_b = (const float*)d_in[5];
    const float* bn_m = (const float*)d_in[6];
    const float* bn_v = (const float*)d_in[7];
    const float* fciW = (const float*)d_in[8];
    const float* fcib = (const float*)d_in[9];
    const float* Wih1 = (const float*)d_in[10];
    const float* Whh1 = (const float*)d_in[11];
    const float* bih1 = (const float*)d_in[12];
    const float* bhh1 = (const float*)d_in[13];
    const float* Wih2 = (const float*)d_in[14];
    const float* Whh2 = (const float*)d_in[15];
    const float* bih2 = (const float*)d_in[16];
    const float* bhh2 = (const float*)d_in[17];
    const float* Wih3 = (const float*)d_in[18];
    const float* Whh3 = (const float*)d_in[19];
    const float* bih3 = (const float*)d_in[20];
    const float* bhh3 = (const float*)d_in[21];
    const float* fcoW = (const float*)d_in[22];
    const float* fcob = (const float*)d_in[23];
    float* ws  = (float*)d_ws;
    float* out = (float*)d_out;

    hipLaunchKernelGGL(prep_transpose2, dim3(625), dim3(256), 0, stream, Wih1, fciW, ws);
    hipLaunchKernelGGL(prep_frags, dim3(340), dim3(256), 0, stream,
                       Whh1, Wih2, Whh2, Wih3, Whh3, fcoW, ws);
    hipLaunchKernelGGL(prep_input, dim3(kB), dim3(256), 0, stream,
                       enc, bn_g, bn_b, bn_m, bn_v, fcib, bih1, ws);
    hipLaunchKernelGGL(gru_main, dim3(NWG), dim3(1024), 0, stream,
                       ws, h1in, h2in, h3in, bhh1, bih2, bhh2, bih3, bhh3, fcob, out);
}